// Round 14
// baseline (237.458 us; speedup 1.0000x reference)
//
#include <hip/hip_runtime.h>
#include <hip/hip_fp16.h>

typedef int v4i __attribute__((ext_vector_type(4)));

#define QMAXF 127.0f
#define EPSF 1e-8f

// ---------------------------------------------------------------------------
// Fused per-row quantization (validated round 13).
// ---------------------------------------------------------------------------
__global__ __launch_bounds__(256) void quant_all(
    const float* __restrict__ w, const float* __restrict__ x,
    signed char* __restrict__ wq, signed char* __restrict__ xq,
    float* __restrict__ wsc, float* __restrict__ xsc, int Nw, int ncols) {
  const int b = blockIdx.x;
  const bool is_w = b < Nw;
  const int row = is_w ? b : b - Nw;
  const float* __restrict__ src = is_w ? w : x;
  signed char* __restrict__ q = is_w ? wq : xq;
  float* __restrict__ scale = is_w ? wsc : xsc;

  const int t = threadIdx.x;
  const float4* s4 = (const float4*)(src + (size_t)row * ncols);

  float4 v[4];
  float am = 0.f;
#pragma unroll
  for (int p = 0; p < 4; ++p) {
    v[p] = s4[p * 256 + t];
    am = fmaxf(am, fmaxf(fmaxf(fabsf(v[p].x), fabsf(v[p].y)),
                         fmaxf(fabsf(v[p].z), fabsf(v[p].w))));
  }
#pragma unroll
  for (int off = 32; off > 0; off >>= 1) am = fmaxf(am, __shfl_xor(am, off));
  __shared__ float red[4];
  if ((t & 63) == 0) red[t >> 6] = am;
  __syncthreads();
  am = fmaxf(fmaxf(red[0], red[1]), fmaxf(red[2], red[3]));

  const float s = fmaxf(am, EPSF) / QMAXF;

  uint32_t* qrow = (uint32_t*)(q + (size_t)row * ncols);
#pragma unroll
  for (int p = 0; p < 4; ++p) {
    float fx = fminf(fmaxf(rintf(v[p].x / s), -QMAXF), QMAXF);
    float fy = fminf(fmaxf(rintf(v[p].y / s), -QMAXF), QMAXF);
    float fz = fminf(fmaxf(rintf(v[p].z / s), -QMAXF), QMAXF);
    float fw = fminf(fmaxf(rintf(v[p].w / s), -QMAXF), QMAXF);
    qrow[p * 256 + t] = ((uint32_t)((int)fx & 0xff)) |
                        ((uint32_t)((int)fy & 0xff) << 8) |
                        ((uint32_t)((int)fz & 0xff) << 16) |
                        ((uint32_t)((int)fw & 0xff) << 24);
  }
  if (t == 0) scale[row] = is_w ? __half2float(__float2half(s)) : s;
}

// ---------------------------------------------------------------------------
// 256x256 int8 GEMM — round-14: 16 WAVES (1024 thr), 64x64 per wave,
// 4 waves/SIMD (TLP escape from the 2-wave lockstep sum).
//   acc shrinks 128->64 regs/wave => total ~122 <= 128 => 4 waves/SIMD.
//   Validated r6 components unchanged: LDS [2][256][128] A+B, (row&7)<<4
//   XOR swizzle both sides, 2-window K-tile, counted-vmcnt ledger (scaled
//   to 1-gload units: entering kt in-flight=2; w1 +2 {SA1,SB1(kt+1)};
//   w2 +2 {SA0,SB0(kt+2)}; boundary vmcnt(2); tail vmcnt(0); prologue 6
//   issued -> vmcnt(2)). Homogeneous gload_lds queue (r8/r9 lesson).
//   Read instr pattern identical to r6 (16-lane b128, conflict-free).
// ---------------------------------------------------------------------------
__device__ __forceinline__ void gload16(const void* g, void* l) {
  __builtin_amdgcn_global_load_lds(
      (const __attribute__((address_space(1))) void*)g,
      (__attribute__((address_space(3))) void*)l, 16, 0, 0);
}

// A half-stage (16 KB = 1 gload/thread): rows {br0+[0,64), br0+128+[0,64)}
#define STAGE_A(dst, br0, ktoff)                                            \
  do {                                                                      \
    const int ar_ = (br0) + (lr & 63) + ((lr >> 6) << 7);                   \
    gload16(Ap + (size_t)ar_ * K + (ktoff) + scsw,                          \
            (dst) + ar_ * 128 + sc);                                        \
  } while (0)

// B half-stage (16 KB = 1 gload/thread): stripes {nh*32+[0,32)+64k}
#define STAGE_B(dst, nh, ktoff)                                             \
  do {                                                                      \
    const int br_ = (nh)*32 + (lr & 31) + ((lr >> 5) << 6);                 \
    gload16(Bp + (size_t)br_ * K + (ktoff) + scsw,                          \
            (dst) + br_ * 128 + sc);                                        \
  } while (0)

// A-fragments for m-tile pair MB..MB+1 (4 x ds_read_b128)
#define READ_AF(AF, MB)                                                     \
  _Pragma("unroll") for (int mi = 0; mi < 2; ++mi)                          \
      _Pragma("unroll") for (int ks = 0; ks < 2; ++ks)                      \
          AF[mi][ks] = *(const v4i*)(Ad + (arow + ((MB) + mi) * 16) * 128 + \
                                     ((ac0 + ks * 64) ^ axor))

// All B-fragments (8 x ds_read_b128), read once per K-tile in w1
#define READ_BF_ALL()                                                       \
  _Pragma("unroll") for (int ni = 0; ni < 4; ++ni)                          \
      _Pragma("unroll") for (int ks = 0; ks < 2; ++ks)                      \
          bf[ni][ks] = *(const v4i*)(Bd + (brow + ni * 16) * 128 +          \
                                     ((ac0 + ks * 64) ^ bxor))

// 16 MFMAs: m-tiles MB..MB+1 x n-tiles 0..3 x ks 0..1
#define MFMA_HALF(MB, AF)                                                   \
  _Pragma("unroll") for (int ks = 0; ks < 2; ++ks)                          \
      _Pragma("unroll") for (int mi = 0; mi < 2; ++mi)                      \
          _Pragma("unroll") for (int ni = 0; ni < 4; ++ni)                  \
              acc[(MB) + mi][ni] = __builtin_amdgcn_mfma_i32_16x16x64_i8(   \
                  AF[mi][ks], bf[ni][ks], acc[(MB) + mi][ni], 0, 0, 0)

__global__ __launch_bounds__(1024, 4) void gemm_i8(
    const signed char* __restrict__ A,  // xq [M][K]
    const signed char* __restrict__ B,  // wq [N][K]
    const float* __restrict__ xsc,      // [M]
    const float* __restrict__ wsc,      // [N]
    const float* __restrict__ bias,     // [N]
    float* __restrict__ out, int M, int N, int K) {
  __shared__ __align__(16) signed char lds[131072];
  signed char* const ldsA = lds;          // [2][256][128]
  signed char* const ldsB = lds + 65536;  // [2][256][128]

  const int tid = threadIdx.x;
  const int lane = tid & 63;
  const int wid = tid >> 6;  // 0..15
  const int wm = wid >> 2;   // 0..3
  const int wn = wid & 3;    // 0..3
  const int bm0 = blockIdx.x * 256;
  const int bn0 = blockIdx.y * 256;

  const signed char* Ap = A + (size_t)bm0 * K;
  const signed char* Bp = B + (size_t)bn0 * K;

  // staging geometry: thread covers one 16B chunk of a 128-row half-stage
  const int lr = tid >> 3;                // 0..127
  const int sc = (tid & 7) << 4;          // linear dest col byte
  const int scsw = sc ^ ((lr & 7) << 4);  // pre-swizzled SOURCE col
  // (row & 7) == (lr & 7) for all staged rows: offsets 32/64/128 are =0 mod 8

  // read geometry (per lane) — r6-validated conflict-free pattern
  const int arow = wm * 64 + (lane & 15);
  const int brow = wn * 64 + (lane & 15);
  const int ac0 = (lane >> 4) << 4;
  const int axor = (arow & 7) << 4;
  const int bxor = (brow & 7) << 4;

  v4i acc[4][4];  // 64 regs
#pragma unroll
  for (int i = 0; i < 4; ++i)
#pragma unroll
    for (int j = 0; j < 4; ++j) acc[i][j] = (v4i){0, 0, 0, 0};

  const int NKT = K >> 7;  // 32 K-tiles of 128 bytes

  // ---- prologue: kt0 fully + {SA0,SB0}(kt1); keep 2 in flight ----
  STAGE_A(ldsA, 0, 0);            // SA0(0)
  STAGE_B(ldsB, 0, 0);            // SB0(0)
  STAGE_A(ldsA, 64, 0);           // SA1(0)
  STAGE_B(ldsB, 1, 0);            // SB1(0)
  STAGE_A(ldsA + 32768, 0, 128);  // SA0(1)
  STAGE_B(ldsB + 32768, 0, 128);  // SB0(1)
  asm volatile("s_waitcnt vmcnt(2)" ::: "memory");
  __builtin_amdgcn_sched_barrier(0);
  __builtin_amdgcn_s_barrier();

  for (int kt = 0; kt < NKT; ++kt) {
    const int d = kt & 1;
    const signed char* Ad = ldsA + d * 32768;
    const signed char* Bd = ldsB + d * 32768;
    signed char* const An = ldsA + (d ^ 1) * 32768;
    signed char* const Bn = ldsB + (d ^ 1) * 32768;
    const int ko1 = (kt + 1) << 7;
    const int ko2 = (kt + 2) << 7;

    v4i af[2][2];  // A-pair fragments (w1: mi 0-1, w2: mi 2-3; SSA-renamed)
    v4i bf[4][2];  // all B fragments (read w1, used both windows)

    // ---- window 1: reads(12) -> stages(SA1,SB1 kt+1) -> 16 MFMA ----
    READ_AF(af, 0);
    READ_BF_ALL();
    if (kt + 1 < NKT) {
      STAGE_A(An, 64, ko1);
      STAGE_B(Bn, 1, ko1);
    }
    __builtin_amdgcn_s_setprio(1);
    MFMA_HALF(0, af);
    __builtin_amdgcn_s_setprio(0);
    __builtin_amdgcn_s_barrier();

    // ---- window 2: reads(4) -> stages(SA0,SB0 kt+2) -> 16 MFMA ----
    READ_AF(af, 2);
    if (kt + 2 < NKT) {
      STAGE_A((signed char*)Ad, 0, ko2);
      STAGE_B((signed char*)Bd, 0, ko2);
    }
    __builtin_amdgcn_s_setprio(1);
    MFMA_HALF(2, af);
    __builtin_amdgcn_s_setprio(0);
    // counted drain in steady state; full drain once staging stops
    if (kt < NKT - 2) {
      asm volatile("s_waitcnt vmcnt(2)" ::: "memory");
    } else {
      asm volatile("s_waitcnt vmcnt(0)" ::: "memory");
    }
    __builtin_amdgcn_sched_barrier(0);
    __builtin_amdgcn_s_barrier();
  }

  // ---- epilogue: dequant + fp16-roundtripped bias, fp32 store ----
#pragma unroll
  for (int mi = 0; mi < 4; ++mi) {
    const int m0 = bm0 + wm * 64 + mi * 16 + ((lane >> 4) << 2);
    const float4 xs = *(const float4*)&xsc[m0];
    const float xsv[4] = {xs.x, xs.y, xs.z, xs.w};
#pragma unroll
    for (int ni = 0; ni < 4; ++ni) {
      const int n = bn0 + wn * 64 + ni * 16 + (lane & 15);
      const float wsn = wsc[n];
      const float bn_ = __half2float(__float2half(bias[n]));
#pragma unroll
      for (int r = 0; r < 4; ++r) {
        out[(size_t)(m0 + r) * N + n] =
            (float)acc[mi][ni][r] * xsv[r] * wsn + bn_;
      }
    }
  }
}

extern "C" void kernel_launch(void* const* d_in, const int* in_sizes, int n_in,
                              void* d_out, int out_size, void* d_ws,
                              size_t ws_size, hipStream_t stream) {
  const float* x = (const float*)d_in[0];     // [M][K] fp32
  const float* w = (const float*)d_in[1];     // [N][K] fp32
  const float* bias = (const float*)d_in[2];  // [N] fp32
  float* out = (float*)d_out;

  const int K = 4096;
  const int Nw = in_sizes[1] / K;  // 4096
  const int M = in_sizes[0] / K;   // 8192

  signed char* wq = (signed char*)d_ws;
  signed char* xq = wq + (size_t)Nw * K;
  float* wsc = (float*)(xq + (size_t)M * K);
  float* xsc = wsc + Nw;

  quant_all<<<Nw + M, 256, 0, stream>>>(w, x, wq, xq, wsc, xsc, Nw, K);

  dim3 g2(M / 256, Nw / 256, 1);
  gemm_i8<<<g2, 1024, 0, stream>>>(xq, wq, xsc, wsc, bias, out, M, Nw, K);
}